// Round 19
// baseline (292.647 us; speedup 1.0000x reference)
//
#include <hip/hip_runtime.h>
#include <stdint.h>

typedef unsigned short u16;
typedef __bf16 bf16x8 __attribute__((ext_vector_type(8)));
typedef float f32x4 __attribute__((ext_vector_type(4)));

#define BB 4
#define SS 1024
#define DD 1024
#define HH 16
#define DHH 64
#define FF 4096
#define NEGV -1000000.0f
#define LOG2E 1.4426950408889634f

__device__ __forceinline__ u16 f2b(float f) {
    uint32_t u = __float_as_uint(f);
    u += 0x7fff + ((u >> 16) & 1);
    return (u16)(u >> 16);
}
__device__ __forceinline__ float b2f(u16 u) {
    return __uint_as_float(((uint32_t)u) << 16);
}
__device__ __forceinline__ float exp2_raw(float x) {
    float r;
    asm volatile("v_exp_f32 %0, %1" : "=v"(r) : "v"(x));
    return r;
}
__device__ __forceinline__ void async16(const void* gp, void* lp) {
    auto g = reinterpret_cast<const __attribute__((address_space(1))) uint32_t*>(
        reinterpret_cast<uintptr_t>(gp));
    auto l = reinterpret_cast<__attribute__((address_space(3))) uint32_t*>(
        reinterpret_cast<uintptr_t>(lp));
    __builtin_amdgcn_global_load_lds(g, l, 16, 0, 0);
}

// ---------------- mega prep kernel (R16 config: best measured) ----------------
struct W8 { const float* p[8]; };

__device__ __forceinline__ void wtrans_body(const float* __restrict__ W, u16* __restrict__ Wt,
                                            int K, int N, int bx, int by,
                                            u16 (*t)[66]) {
    int n0 = bx * 64, k0 = by * 128;
    int tx = threadIdx.x & 15, r0 = threadIdx.x >> 4;
#pragma unroll
    for (int p = 0; p < 8; ++p) {
        int r = r0 + p * 16;
        float4 v = *reinterpret_cast<const float4*>(&W[(size_t)(k0 + r) * N + n0 + tx * 4]);
        ushort4 o = {f2b(v.x), f2b(v.y), f2b(v.z), f2b(v.w)};
        *reinterpret_cast<ushort4*>(&t[r][tx * 4]) = o;
    }
    __syncthreads();
    int c = threadIdx.x & 31, nq0 = threadIdx.x >> 5;
#pragma unroll
    for (int p = 0; p < 2; ++p) {
        int nq = nq0 + p * 8;
        ushort4 va[4];
#pragma unroll
        for (int i = 0; i < 4; ++i)
            va[i] = *reinterpret_cast<const ushort4*>(&t[c * 4 + i][nq * 4]);
        ushort4 ot[4];
        ot[0] = {va[0].x, va[1].x, va[2].x, va[3].x};
        ot[1] = {va[0].y, va[1].y, va[2].y, va[3].y};
        ot[2] = {va[0].z, va[1].z, va[2].z, va[3].z};
        ot[3] = {va[0].w, va[1].w, va[2].w, va[3].w};
#pragma unroll
        for (int j = 0; j < 4; ++j)
            *reinterpret_cast<ushort4*>(&Wt[(size_t)(n0 + nq * 4 + j) * K + k0 + c * 4]) = ot[j];
    }
}

__global__ void prep_kernel(const float* __restrict__ X, const float* __restrict__ ENC,
                            u16* __restrict__ XBF, u16* __restrict__ ENCB,
                            W8 w8, u16* __restrict__ WTsq,
                            const float* __restrict__ Wf1, u16* __restrict__ WTf1,
                            const float* __restrict__ Wf2, u16* __restrict__ WTf2,
                            const float* __restrict__ bq1, const float* __restrict__ bk1,
                            const float* __restrict__ bv1, float* __restrict__ B1,
                            const float* __restrict__ bk2, const float* __restrict__ bv2,
                            float* __restrict__ B2)
{
    __shared__ u16 t[128][66];
    const int bid = blockIdx.x, tid = threadIdx.x;
    if (bid < 4096) {
        int i = bid * 256 + tid;
        float4 v = reinterpret_cast<const float4*>(X)[i];
        ushort4 o = {f2b(v.x), f2b(v.y), f2b(v.z), f2b(v.w)};
        reinterpret_cast<ushort4*>(XBF)[i] = o;
    } else if (bid < 8192) {
        int i = (bid - 4096) * 256 + tid;
        float4 v = reinterpret_cast<const float4*>(ENC)[i];
        ushort4 o = {f2b(v.x), f2b(v.y), f2b(v.z), f2b(v.w)};
        reinterpret_cast<ushort4*>(ENCB)[i] = o;
    } else if (bid < 9216) {
        int idx = bid - 8192;
        int z = idx >> 7, rem = idx & 127;
        wtrans_body(w8.p[z], WTsq + (size_t)z * 1024 * 1024, 1024, 1024, rem & 15, rem >> 4, t);
    } else if (bid < 9728) {
        int idx = bid - 9216;
        wtrans_body(Wf1, WTf1, DD, FF, idx & 63, idx >> 6, t);
    } else if (bid < 10240) {
        int idx = bid - 9728;
        wtrans_body(Wf2, WTf2, FF, DD, idx & 15, idx >> 4, t);
    } else {
        int idx = bid - 10240;
        if (idx < 12) {
            int i = idx * 256 + tid;
            float v = (i < 1024) ? bq1[i] : (i < 2048) ? bk1[i - 1024] : bv1[i - 2048];
            B1[i] = v;
        } else {
            int i = (idx - 12) * 256 + tid;
            float v = (i < 1024) ? bk2[i] : bv2[i - 1024];
            B2[i] = v;
        }
    }
}

// ---------------- 128^2-tile GEMM (2-barrier structure) ----------------
template<int BM, bool OUT_BF16, bool RELU, int KSPLIT = 1, bool VOUT = false>
__global__ __launch_bounds__(256, 3) void gemm_bt_kernel(
    const u16* __restrict__ A, const u16* __restrict__ Bt,
    const float* __restrict__ bias, void* __restrict__ Cv,
    int M, int N, int K, int qcols, float qscale,
    int vcol0 = 0, u16* __restrict__ VT = nullptr)
{
    constexpr int MR = BM / 32;
    __shared__ __attribute__((aligned(16))) u16 As[BM][64];
    __shared__ __attribute__((aligned(16))) u16 Bs[128][64];
    const int tid = threadIdx.x;
    const int lane = tid & 63, wid = tid >> 6;
    const int wr = wid >> 1, wc = wid & 1;
    const int m0 = blockIdx.x * BM, n0 = blockIdx.y * 128;
    const int kz = (KSPLIT > 1) ? blockIdx.z : 0;
    const int Kc = K / KSPLIT;
    const int k0 = kz * Kc;
    const int arow = lane & 15;
    const int kseg = (lane >> 4) * 8;
    const int srow = lane >> 3;
    const int scol = ((lane & 7) ^ srow) * 8;
    const int rswz = (arow & 7) << 3;
    const f32x4 z4 = {0.f, 0.f, 0.f, 0.f};

    f32x4 acc[MR][4];
#pragma unroll
    for (int i = 0; i < MR; ++i)
#pragma unroll
        for (int j = 0; j < 4; ++j) acc[i][j] = z4;

    for (int kt = k0; kt < k0 + Kc; kt += 64) {
        __syncthreads();
#pragma unroll
        for (int i = 0; i < MR; ++i) {
            int ch = wid + i * 4;
            async16(&A[(size_t)(m0 + ch * 8 + srow) * K + kt + scol], &As[ch * 8][0]);
        }
#pragma unroll
        for (int i = 0; i < 4; ++i) {
            int ch = wid + i * 4;
            async16(&Bt[(size_t)(n0 + ch * 8 + srow) * K + kt + scol], &Bs[ch * 8][0]);
        }
        __syncthreads();
#pragma unroll
        for (int ks = 0; ks < 2; ++ks) {
            const int cswz = (ks * 32 + kseg) ^ rswz;
            bf16x8 af[MR], bfr[4];
#pragma unroll
            for (int mi = 0; mi < MR; ++mi)
                af[mi] = *reinterpret_cast<const bf16x8*>(&As[wr * (BM / 2) + mi * 16 + arow][cswz]);
#pragma unroll
            for (int ni = 0; ni < 4; ++ni)
                bfr[ni] = *reinterpret_cast<const bf16x8*>(&Bs[wc * 64 + ni * 16 + arow][cswz]);
#pragma unroll
            for (int mi = 0; mi < MR; ++mi)
#pragma unroll
                for (int ni = 0; ni < 4; ++ni)
                    acc[mi][ni] = __builtin_amdgcn_mfma_f32_16x16x32_bf16(af[mi], bfr[ni], acc[mi][ni], 0, 0, 0);
        }
    }
    const int rrow = (lane >> 4) * 4;
#pragma unroll
    for (int mi = 0; mi < MR; ++mi)
#pragma unroll
        for (int ni = 0; ni < 4; ++ni) {
            int col = n0 + wc * 64 + ni * 16 + arow;
            float bv = (kz == 0) ? bias[col] : 0.f;
            float sc = (col < qcols) ? qscale : 1.f;
            float vv[4];
#pragma unroll
            for (int r = 0; r < 4; ++r) {
                float v = (acc[mi][ni][r] + bv) * sc;
                if (RELU) v = fmaxf(v, 0.f);
                vv[r] = v;
            }
            int row0 = m0 + wr * (BM / 2) + mi * 16 + rrow;
            if (VOUT && col >= vcol0) {
                int hh = (col - vcol0) >> 6, dd = (col - vcol0) & 63;
                int bb = row0 >> 10, s0 = row0 & 1023;
                ushort4 hv = {f2b(vv[0]), f2b(vv[1]), f2b(vv[2]), f2b(vv[3])};
                *reinterpret_cast<ushort4*>(&VT[((size_t)(bb * 16 + hh) * 64 + dd) * 1024 + s0]) = hv;
            } else {
#pragma unroll
                for (int r = 0; r < 4; ++r) {
                    size_t idx = (size_t)kz * M * N + (size_t)(row0 + r) * N + col;
                    if (OUT_BF16) ((u16*)Cv)[idx] = f2b(vv[r]);
                    else          ((float*)Cv)[idx] = vv[r];
                }
            }
        }
}

// ---------------- 256 x (NFRAG*64) tile 8-wave deep-pipelined GEMM ----------------
template<int NFRAG, bool OUT_BF16, bool RELU, int KSPLIT = 1, bool VOUT = false>
__global__ __launch_bounds__(512, 2) void gemm256_kernel(
    const u16* __restrict__ A, const u16* __restrict__ Bt,
    const float* __restrict__ bias, void* __restrict__ Cv,
    int M, int N, int K, int qcols, float qscale,
    int vcol0 = 0, u16* __restrict__ VT = nullptr)
{
    constexpr int BN = NFRAG * 64;
    __shared__ __attribute__((aligned(16))) u16 As[2][256][64];
    __shared__ __attribute__((aligned(16))) u16 Bs[2][BN][64];
    const int tid = threadIdx.x, lane = tid & 63, wid = tid >> 6;
    const int wr = wid >> 2, wc = wid & 3;
    const int gx = gridDim.x, nwg = gridDim.x * gridDim.y;
    int bid = blockIdx.y * gx + blockIdx.x;
    int swz = (bid & 7) * (nwg >> 3) + (bid >> 3);
    const int m0 = (swz % gx) * 256, n0 = (swz / gx) * BN;
    const int kz = (KSPLIT > 1) ? blockIdx.z : 0;
    const int Kc = K / KSPLIT, k0 = kz * Kc, NT = Kc >> 6;
    const int a = lane & 15, g = lane >> 4;
    const int srow = lane >> 3;
    const int scol = ((lane & 7) ^ srow) * 8;
    const int rswz = (a & 7) << 3;
    const f32x4 z4 = {0.f, 0.f, 0.f, 0.f};

    f32x4 acc[8][NFRAG];
#pragma unroll
    for (int i = 0; i < 8; ++i)
#pragma unroll
        for (int j = 0; j < NFRAG; ++j) acc[i][j] = z4;

    auto stageA = [&](int t, int h) {
        int kt = k0 + t * 64;
#pragma unroll
        for (int i = 0; i < 2; ++i) {
            int row = h * 128 + (wid * 2 + i) * 8;
            async16(&A[(size_t)(m0 + row + srow) * K + kt + scol], &As[t & 1][row][0]);
        }
    };
    auto stageBs = [&](int t, int s) {
        int kt = k0 + t * 64;
        int row = s * 64 + wid * 8;
        async16(&Bt[(size_t)(n0 + row + srow) * K + kt + scol], &Bs[t & 1][row][0]);
    };
    auto stageBall = [&](int t) {
#pragma unroll
        for (int s = 0; s < NFRAG; ++s) stageBs(t, s);
    };

    stageA(0, 0); stageA(0, 1); stageBall(0);
    stageA(1, 0); stageA(1, 1); stageBall(1);
    if (NFRAG == 4) asm volatile("s_waitcnt vmcnt(8)" ::: "memory");
    else            asm volatile("s_waitcnt vmcnt(7)" ::: "memory");
    __builtin_amdgcn_s_barrier();
    asm volatile("" ::: "memory");

    for (int t = 0; t < NT; ++t) {
        const int b = t & 1;
        bf16x8 bf[NFRAG][2];
#pragma unroll
        for (int p = 0; p < 4; ++p) {
            bf16x8 af[2][2];
#pragma unroll
            for (int m2 = 0; m2 < 2; ++m2)
#pragma unroll
                for (int ks = 0; ks < 2; ++ks)
                    af[m2][ks] = *reinterpret_cast<const bf16x8*>(
                        &As[b][wr * 128 + (p * 2 + m2) * 16 + a][(ks * 32 + g * 8) ^ rswz]);
            if (p == 0) {
#pragma unroll
                for (int ni = 0; ni < NFRAG; ++ni)
#pragma unroll
                    for (int ks = 0; ks < 2; ++ks)
                        bf[ni][ks] = *reinterpret_cast<const bf16x8*>(
                            &Bs[b][wc * (NFRAG * 16) + ni * 16 + a][(ks * 32 + g * 8) ^ rswz]);
            }
            if (p == 0 && t >= 1 && t + 1 < NT) stageA(t + 1, 0);
            if (p == 1 && t >= 1 && t + 1 < NT) stageA(t + 1, 1);
            if (p == 2 && t + 2 < NT) {
                stageBs(t + 2, 0);
                if (NFRAG >= 2) stageBs(t + 2, 1);
            }
            if (p == 3 && t + 2 < NT) {
#pragma unroll
                for (int s = 2; s < NFRAG; ++s) stageBs(t + 2, s);
            }
            asm volatile("" ::: "memory");
            __builtin_amdgcn_s_barrier();
            asm volatile("" ::: "memory");
            __builtin_amdgcn_s_setprio(1);
#pragma unroll
            for (int ks = 0; ks < 2; ++ks)
#pragma unroll
                for (int m2 = 0; m2 < 2; ++m2)
#pragma unroll
                    for (int ni = 0; ni < NFRAG; ++ni)
                        acc[p * 2 + m2][ni] = __builtin_amdgcn_mfma_f32_16x16x32_bf16(
                            af[m2][ks], bf[ni][ks], acc[p * 2 + m2][ni], 0, 0, 0);
            __builtin_amdgcn_s_setprio(0);
        }
        if (t < NT - 1) {
            if (t < NT - 2) {
                if (NFRAG == 4) asm volatile("s_waitcnt vmcnt(4)" ::: "memory");
                else            asm volatile("s_waitcnt vmcnt(3)" ::: "memory");
            } else {
                asm volatile("s_waitcnt vmcnt(0)" ::: "memory");
            }
            __builtin_amdgcn_s_barrier();
            asm volatile("" ::: "memory");
        }
    }

    const int rrow = g * 4;
#pragma unroll
    for (int mi = 0; mi < 8; ++mi)
#pragma unroll
        for (int ni = 0; ni < NFRAG; ++ni) {
            int col = n0 + wc * (NFRAG * 16) + ni * 16 + a;
            float bv = (kz == 0) ? bias[col] : 0.f;
            float sc = (col < qcols) ? qscale : 1.f;
            float vv[4];
#pragma unroll
            for (int r = 0; r < 4; ++r) {
                float v = (acc[mi][ni][r] + bv) * sc;
                if (RELU) v = fmaxf(v, 0.f);
                vv[r] = v;
            }
            int row0 = m0 + wr * 128 + mi * 16 + rrow;
            if (VOUT && col >= vcol0) {
                int hh = (col - vcol0) >> 6, dd = (col - vcol0) & 63;
                int bb = row0 >> 10, s0 = row0 & 1023;
                ushort4 hv = {f2b(vv[0]), f2b(vv[1]), f2b(vv[2]), f2b(vv[3])};
                *reinterpret_cast<ushort4*>(&VT[((size_t)(bb * 16 + hh) * 64 + dd) * 1024 + s0]) = hv;
            } else {
#pragma unroll
                for (int r = 0; r < 4; ++r) {
                    size_t idx = (size_t)kz * M * N + (size_t)(row0 + r) * N + col;
                    if (OUT_BF16) ((u16*)Cv)[idx] = f2b(vv[r]);
                    else          ((float*)Cv)[idx] = vv[r];
                }
            }
        }
}

// ---------------- flash attention (unchanged) ----------------
__global__ __launch_bounds__(512, 4) void flash_attn_kernel(
    const u16* __restrict__ Q, int ldq, const u16* __restrict__ Kp, int ldk,
    const u16* __restrict__ VT, u16* __restrict__ O,
    const int* __restrict__ vlens, int causal)
{
    __shared__ __attribute__((aligned(16))) u16 Ks[128][64];
    __shared__ __attribute__((aligned(16))) u16 Vs[64][128];
    __shared__ __attribute__((aligned(16))) u16 Ps[128][64];
    const int tid = threadIdx.x, lane = tid & 63, wid = tid >> 6;
    const int bh = blockIdx.x;
    int qb = blockIdx.y;
    if (causal) qb = (bh & 1) ? (7 - qb) : qb;
    const int b = bh >> 4, h = bh & 15;
    const int q0 = qb * 128;
    const int a = lane & 15;
    const int g = lane >> 4;
    const int kseg = g * 8;
    const int srow = lane >> 3;
    const int scol = ((lane & 7) ^ srow) * 8;
    const int vrow = lane >> 4;
    const int rswz = (a & 7) << 3;
    const int vswz = a << 3;
    const f32x4 z4 = {0.f, 0.f, 0.f, 0.f};

    bf16x8 qf[2];
#pragma unroll
    for (int ks = 0; ks < 2; ++ks)
        qf[ks] = *reinterpret_cast<const bf16x8*>(
            &Q[(size_t)(b * SS + q0 + wid * 16 + a) * ldq + h * DHH + ks * 32 + kseg]);

    float m_run = -3e38f, l_run = 0.f;
    f32x4 o[4];
#pragma unroll
    for (int nd = 0; nd < 4; ++nd) o[nd] = z4;

    int vl = causal ? SS : vlens[b];
    int ntiles = causal ? (qb + 1) : ((vl + 127) >> 7);

    for (int kt = 0; kt < ntiles; ++kt) {
        const int kv0 = kt * 128;
        __syncthreads();
#pragma unroll
        for (int i = 0; i < 2; ++i) {
            int ch = wid + i * 8;
            async16(&Kp[(size_t)(b * SS + kv0 + ch * 8 + srow) * ldk + h * DHH + scol], &Ks[ch * 8][0]);
            int cv = wid + i * 8;
            int vs = (cv * 4 + vrow) & 15;
            async16(&VT[(size_t)(bh * DHH + cv * 4 + vrow) * SS + kv0 + ((lane & 15) ^ vs) * 8], &Vs[cv * 4][0]);
        }
        __syncthreads();

        f32x4 st[8];
#pragma unroll
        for (int ni = 0; ni < 8; ++ni) st[ni] = z4;
        __builtin_amdgcn_s_setprio(1);
#pragma unroll
        for (int ks = 0; ks < 2; ++ks) {
            const int cswz = (ks * 32 + kseg) ^ rswz;
            bf16x8 kf[8];
#pragma unroll
            for (int ni = 0; ni < 8; ++ni)
                kf[ni] = *reinterpret_cast<const bf16x8*>(&Ks[ni * 16 + a][cswz]);
#pragma unroll
            for (int ni = 0; ni < 8; ++ni)
                st[ni] = __builtin_amdgcn_mfma_f32_16x16x32_bf16(kf[ni], qf[ks], st[ni], 0, 0, 0);
        }
        __builtin_amdgcn_s_setprio(0);

        bool domask = causal ? (kt == qb) : (kv0 + 128 > vl);
        if (domask) {
            const int qg = q0 + wid * 16 + a;
#pragma unroll
            for (int ni = 0; ni < 8; ++ni)
#pragma unroll
                for (int r = 0; r < 4; ++r) {
                    int cg = kv0 + ni * 16 + 4 * g + r;
                    bool keep = causal ? (cg <= qg) : (cg < vl);
                    if (!keep) st[ni][r] = NEGV;
                }
        }

        float tm = -3e38f;
#pragma unroll
        for (int ni = 0; ni < 8; ++ni)
#pragma unroll
            for (int r = 0; r < 4; ++r) tm = fmaxf(tm, st[ni][r]);
        tm = fmaxf(tm, __shfl_xor(tm, 16));
        tm = fmaxf(tm, __shfl_xor(tm, 32));
        bool need = __any(tm > m_run + 11.0f);
        float corr = 1.f;
        if (need) {
            float nm = fmaxf(m_run, tm);
            corr = exp2_raw(m_run - nm);
            m_run = nm;
        }
        float rs = 0.f;
#pragma unroll
        for (int ni = 0; ni < 8; ++ni)
#pragma unroll
            for (int r = 0; r < 4; ++r) {
                float p = exp2_raw(st[ni][r] - m_run);
                st[ni][r] = p;
                rs += p;
            }
        rs += __shfl_xor(rs, 16);
        rs += __shfl_xor(rs, 32);
        l_run = l_run * corr + rs;

        if (need) {
#pragma unroll
            for (int r = 0; r < 4; ++r) {
                float cr = __shfl(corr, (lane & 48) + 4 * g + r);
#pragma unroll
                for (int nd = 0; nd < 4; ++nd) o[nd][r] *= cr;
            }
        }

#pragma unroll
        for (int hh = 0; hh < 2; ++hh) {
#pragma unroll
            for (int ni4 = 0; ni4 < 4; ++ni4) {
                int ni = hh * 4 + ni4;
                uint2 pw;
                pw.x = (uint32_t)f2b(st[ni][0]) | ((uint32_t)f2b(st[ni][1]) << 16);
                pw.y = (uint32_t)f2b(st[ni][2]) | ((uint32_t)f2b(st[ni][3]) << 16);
                int prow = wid * 16 + a;
                int pcol = (ni4 * 16 + 4 * g) ^ rswz;
                *reinterpret_cast<uint2*>(&Ps[prow][pcol]) = pw;
            }
            __builtin_amdgcn_s_setprio(1);
#pragma unroll
            for (int kk = 0; kk < 2; ++kk) {
                const int kf_ = hh * 2 + kk;
                const int pswz = (kk * 32 + kseg) ^ rswz;
                const int cvswz = (kf_ * 32 + kseg) ^ vswz;
                bf16x8 pa, vb[4];
                pa = *reinterpret_cast<const bf16x8*>(&Ps[wid * 16 + a][pswz]);
#pragma unroll
                for (int nd = 0; nd < 4; ++nd)
                    vb[nd] = *reinterpret_cast<const bf16x8*>(&Vs[nd * 16 + a][cvswz]);
#pragma unroll
                for (int nd = 0; nd < 4; ++nd)
                    o[nd] = __builtin_amdgcn_mfma_f32_16x16x32_bf16(pa, vb[nd], o[nd], 0, 0, 0);
            }
            __builtin_amdgcn_s_setprio(0);
        }
    }

    float il = 1.f / l_run;
#pragma unroll
    for (int r = 0; r < 4; ++r) {
        float ilr = __shfl(il, (lane & 48) + 4 * g + r);
        int row = q0 + wid * 16 + 4 * g + r;
#pragma unroll
        for (int nd = 0; nd < 4; ++nd)
            O[(size_t)(b * SS + row) * DD + h * DHH + nd * 16 + a] = f2b(o[nd][r] * ilr);
    }
}

// ---------------- fused (sum of NP bf16 partials) + residual + LayerNorm ----------------
template<int NP, bool RBF16, bool OUT32>
__global__ void add_ln_kernel(const u16* __restrict__ P, size_t pstride,
                              const void* __restrict__ Rv,
                              const float* __restrict__ g, const float* __restrict__ be,
                              float* __restrict__ out32, u16* __restrict__ out16)
{
    __shared__ float red[4][2];
    const int row = blockIdx.x, tid = threadIdx.x;
    const size_t base = (size_t)row * DD;
    float x0, x1, x2, x3;
    if (RBF16) {
        ushort4 u = *reinterpret_cast<const ushort4*>((const u16*)Rv + base + tid * 4);
        x0 = b2f(u.x); x1 = b2f(u.y); x2 = b2f(u.z); x3 = b2f(u.w);
    } else {
        float4 v = *reinterpret_cast<const float4*>((const float*)Rv + base + tid * 4);
        x0 = v.x; x1 = v.y; x2 = v.z; x3 = v.w;
    }
#pragma unroll
    for (int p = 0; p < NP; ++p) {
        ushort4 u = *reinterpret_cast<const ushort4*>(P + p * pstride + base + tid * 4);
        x0 += b2f(u.x); x1 += b2f(u.y); x2 += b2f(u.z); x3 += b2f(u.w);
    }
    float s = x0 + x1 + x2 + x3;
    float q = x0 * x0 + x1 * x1 + x2 * x2 + x3 * x3;
#pragma unroll
    for (int off = 32; off; off >>= 1) {
        s += __shfl_xor(s, off);
        q += __shfl_xor(q, off);
    }
    if ((tid & 63) == 0) { red[tid >> 6][0] = s; red[tid >> 6][1] = q; }
    __syncthreads();
    s = red[0][0] + red[1][0] + red[2][0] + red[3][0];
    q = red[0][1] + red[1][1] + red[2][1] + red[3][1];
    float mean = s * (1.f / 1024.f);
    float var = q * (1.f / 1024.f) - mean * mean;
    float rstd = rsqrtf(var + 1e-5f);
    int c = tid * 4;
    float o0 = (x0 - mean) * rstd * g[c + 0] + be[c + 0];
    float o1 = (x1 - mean) * rstd * g[c + 1] + be[c + 1];
    float o2 = (x2 - mean) * rstd * g[c + 2] + be[c + 2];
    float o3 = (x3 - mean) * rstd * g[c + 3] + be[c + 3];
    if (OUT32) {
        float4 ov = {o0, o1, o2, o3};
        *reinterpret_cast<float4*>(out32 + base + c) = ov;
    } else {
        ushort4 hv;
        hv.x = f2b(o0); hv.y = f2b(o1); hv.z = f2b(o2); hv.w = f2b(o3);
        *reinterpret_cast<ushort4*>(out16 + base + c) = hv;
    }
}

extern "C" void kernel_launch(void* const* d_in, const int* in_sizes, int n_in,
                              void* d_out, int out_size, void* d_ws, size_t ws_size,
                              hipStream_t stream)
{
    const float* X   = (const float*)d_in[0];
    const float* ENC = (const float*)d_in[1];
    const int*   VL  = (const int*)d_in[2];
    const float* Wq1 = (const float*)d_in[3];  const float* bq1 = (const float*)d_in[4];
    const float* Wk1 = (const float*)d_in[5];  const float* bk1 = (const float*)d_in[6];
    const float* Wv1 = (const float*)d_in[7];  const float* bv1 = (const float*)d_in[8];
    const float* Wo1 = (const float*)d_in[9];  const float* bo1 = (const float*)d_in[10];
    const float* g1  = (const float*)d_in[11]; const float* be1 = (const float*)d_in[12];
    const float* Wq2 = (const float*)d_in[13]; const float* bq2 = (const float*)d_in[14];
    const float* Wk2 = (const float*)d_in[15]; const float* bk2 = (const float*)d_in[16];
    const float* Wv2 = (const float*)d_in[17]; const float* bv2 = (const float*)d_in[18];
    const float* Wo2 = (const float*)d_in[19]; const float* bo2 = (const float*)d_in[20];
    const float* g2  = (const float*)d_in[21]; const float* be2 = (const float*)d_in[22];
    const float* Wf1 = (const float*)d_in[23]; const float* bf1 = (const float*)d_in[24];
    const float* Wf2 = (const float*)d_in[25]; const float* bf2 = (const float*)d_in[26];
    const float* g3  = (const float*)d_in[27]; const float* be3 = (const float*)d_in[28];

    char* ws = (char*)d_ws;
    const size_t MB = 1024 * 1024;
    u16*   XBF  = (u16*)(ws + 0 * MB);
    u16*   ENCB = (u16*)(ws + 8 * MB);
    u16*   WTsq = (u16*)(ws + 16 * MB);
    u16*   WTf1 = (u16*)(ws + 32 * MB);
    u16*   WTf2 = (u16*)(ws + 40 * MB);
    u16*   QKV  = (u16*)(ws + 48 * MB);
    u16*   HF   = (u16*)(ws + 48 * MB);
    u16*   VTb  = (u16*)(ws + 80 * MB);
    u16*   AO   = (u16*)(ws + 88 * MB);
    u16*   P4   = (u16*)(ws + 80 * MB);
    u16*   P16  = (u16*)(ws + 96 * MB);
    u16*   YBF  = (u16*)(ws + 128 * MB);
    u16*   ZBF  = (u16*)(ws + 152 * MB);
    float* B1 = (float*)d_out;
    float* B2 = (float*)d_out + 4096;
    (void)ws_size; (void)in_sizes; (void)n_in; (void)out_size;

    const int M = BB * SS;
    const size_t MN = (size_t)M * DD;
    const float QS = 0.125f * LOG2E;

    W8 w8 = {{Wq1, Wk1, Wv1, Wo1, Wq2, Wk2, Wv2, Wo2}};
    prep_kernel<<<10260, 256, 0, stream>>>(X, ENC, XBF, ENCB, w8, WTsq,
                                           Wf1, WTf1, Wf2, WTf2,
                                           bq1, bk1, bv1, B1, bk2, bv2, B2);

    // ---------- self attention ----------
    gemm256_kernel<3, true, false, 1, true><<<dim3(16, 16), 512, 0, stream>>>(
        XBF, WTsq, B1, QKV, M, 3072, DD, 1024, QS, 2048, VTb);
    flash_attn_kernel<<<dim3(64, 8), 512, 0, stream>>>(QKV, 3072, QKV + 1024, 3072, VTb, AO, VL, 1);
    gemm_bt_kernel<128, true, false, 2><<<dim3(32, 8, 2), 256, 0, stream>>>(AO, WTsq + 3u * 1024 * 1024, bo1, P16, M, DD, DD, 0, 1.f);
    add_ln_kernel<2, true, false><<<M, 256, 0, stream>>>(P16, MN, XBF, g1, be1, nullptr, YBF);

    // ---------- cross attention ----------
    // Q2 on BM=128 (grid 256 = full machine); BM=64 thin tile measured ~9us worse (r13/r14)
    gemm_bt_kernel<128, true, false><<<dim3(32, 8), 256, 0, stream>>>(YBF, WTsq + 4u * 1024 * 1024, bq2, XBF, M, DD, DD, 1024, QS);
    gemm_bt_kernel<128, true, false, 1, true><<<dim3(32, 16), 256, 0, stream>>>(
        ENCB, WTsq + 5u * 1024 * 1024, B2, QKV, M, 2048, DD, 0, 1.f, 1024, VTb);
    flash_attn_kernel<<<dim3(64, 8), 512, 0, stream>>>(XBF, 1024, QKV, 2048, VTb, AO, VL, 0);
    gemm_bt_kernel<128, true, false, 2><<<dim3(32, 8, 2), 256, 0, stream>>>(AO, WTsq + 7u * 1024 * 1024, bo2, P16, M, DD, DD, 0, 1.f);
    add_ln_kernel<2, true, false><<<M, 256, 0, stream>>>(P16, MN, YBF, g2, be2, nullptr, ZBF);

    // ---------- FFN ----------
    gemm256_kernel<4, true, true><<<dim3(16, 16), 512, 0, stream>>>(ZBF, WTf1, bf1, HF, M, FF, DD, 0, 1.f);
    gemm256_kernel<4, true, false, 4><<<dim3(16, 4, 4), 512, 0, stream>>>(HF, WTf2, bf2, P4, M, DD, FF, 0, 1.f);
    add_ln_kernel<4, true, true><<<M, 256, 0, stream>>>(P4, MN, ZBF, g3, be3, (float*)d_out, nullptr);
}

// Round 20
// 287.722 us; speedup vs baseline: 1.0171x; 1.0171x over previous
//
#include <hip/hip_runtime.h>
#include <stdint.h>

typedef unsigned short u16;
typedef __bf16 bf16x8 __attribute__((ext_vector_type(8)));
typedef float f32x4 __attribute__((ext_vector_type(4)));

#define BB 4
#define SS 1024
#define DD 1024
#define HH 16
#define DHH 64
#define FF 4096
#define NEGV -1000000.0f
#define LOG2E 1.4426950408889634f

__device__ __forceinline__ u16 f2b(float f) {
    uint32_t u = __float_as_uint(f);
    u += 0x7fff + ((u >> 16) & 1);
    return (u16)(u >> 16);
}
__device__ __forceinline__ float b2f(u16 u) {
    return __uint_as_float(((uint32_t)u) << 16);
}
__device__ __forceinline__ float exp2_raw(float x) {
    float r;
    asm volatile("v_exp_f32 %0, %1" : "=v"(r) : "v"(x));
    return r;
}
__device__ __forceinline__ void async16(const void* gp, void* lp) {
    auto g = reinterpret_cast<const __attribute__((address_space(1))) uint32_t*>(
        reinterpret_cast<uintptr_t>(gp));
    auto l = reinterpret_cast<__attribute__((address_space(3))) uint32_t*>(
        reinterpret_cast<uintptr_t>(lp));
    __builtin_amdgcn_global_load_lds(g, l, 16, 0, 0);
}

// ---------------- mega prep kernel (R16 config: best measured) ----------------
struct W8 { const float* p[8]; };

__device__ __forceinline__ void wtrans_body(const float* __restrict__ W, u16* __restrict__ Wt,
                                            int K, int N, int bx, int by,
                                            u16 (*t)[66]) {
    int n0 = bx * 64, k0 = by * 128;
    int tx = threadIdx.x & 15, r0 = threadIdx.x >> 4;
#pragma unroll
    for (int p = 0; p < 8; ++p) {
        int r = r0 + p * 16;
        float4 v = *reinterpret_cast<const float4*>(&W[(size_t)(k0 + r) * N + n0 + tx * 4]);
        ushort4 o = {f2b(v.x), f2b(v.y), f2b(v.z), f2b(v.w)};
        *reinterpret_cast<ushort4*>(&t[r][tx * 4]) = o;
    }
    __syncthreads();
    int c = threadIdx.x & 31, nq0 = threadIdx.x >> 5;
#pragma unroll
    for (int p = 0; p < 2; ++p) {
        int nq = nq0 + p * 8;
        ushort4 va[4];
#pragma unroll
        for (int i = 0; i < 4; ++i)
            va[i] = *reinterpret_cast<const ushort4*>(&t[c * 4 + i][nq * 4]);
        ushort4 ot[4];
        ot[0] = {va[0].x, va[1].x, va[2].x, va[3].x};
        ot[1] = {va[0].y, va[1].y, va[2].y, va[3].y};
        ot[2] = {va[0].z, va[1].z, va[2].z, va[3].z};
        ot[3] = {va[0].w, va[1].w, va[2].w, va[3].w};
#pragma unroll
        for (int j = 0; j < 4; ++j)
            *reinterpret_cast<ushort4*>(&Wt[(size_t)(n0 + nq * 4 + j) * K + k0 + c * 4]) = ot[j];
    }
}

__global__ void prep_kernel(const float* __restrict__ X, const float* __restrict__ ENC,
                            u16* __restrict__ XBF, u16* __restrict__ ENCB,
                            W8 w8, u16* __restrict__ WTsq,
                            const float* __restrict__ Wf1, u16* __restrict__ WTf1,
                            const float* __restrict__ Wf2, u16* __restrict__ WTf2,
                            const float* __restrict__ bq1, const float* __restrict__ bk1,
                            const float* __restrict__ bv1, float* __restrict__ B1,
                            const float* __restrict__ bk2, const float* __restrict__ bv2,
                            float* __restrict__ B2)
{
    __shared__ u16 t[128][66];
    const int bid = blockIdx.x, tid = threadIdx.x;
    if (bid < 4096) {
        int i = bid * 256 + tid;
        float4 v = reinterpret_cast<const float4*>(X)[i];
        ushort4 o = {f2b(v.x), f2b(v.y), f2b(v.z), f2b(v.w)};
        reinterpret_cast<ushort4*>(XBF)[i] = o;
    } else if (bid < 8192) {
        int i = (bid - 4096) * 256 + tid;
        float4 v = reinterpret_cast<const float4*>(ENC)[i];
        ushort4 o = {f2b(v.x), f2b(v.y), f2b(v.z), f2b(v.w)};
        reinterpret_cast<ushort4*>(ENCB)[i] = o;
    } else if (bid < 9216) {
        int idx = bid - 8192;
        int z = idx >> 7, rem = idx & 127;
        wtrans_body(w8.p[z], WTsq + (size_t)z * 1024 * 1024, 1024, 1024, rem & 15, rem >> 4, t);
    } else if (bid < 9728) {
        int idx = bid - 9216;
        wtrans_body(Wf1, WTf1, DD, FF, idx & 63, idx >> 6, t);
    } else if (bid < 10240) {
        int idx = bid - 9728;
        wtrans_body(Wf2, WTf2, FF, DD, idx & 15, idx >> 4, t);
    } else {
        int idx = bid - 10240;
        if (idx < 12) {
            int i = idx * 256 + tid;
            float v = (i < 1024) ? bq1[i] : (i < 2048) ? bk1[i - 1024] : bv1[i - 2048];
            B1[i] = v;
        } else {
            int i = (idx - 12) * 256 + tid;
            float v = (i < 1024) ? bk2[i] : bv2[i - 1024];
            B2[i] = v;
        }
    }
}

// ---------------- 128^2-tile GEMM (2-barrier structure) ----------------
template<int BM, bool OUT_BF16, bool RELU, int KSPLIT = 1, bool VOUT = false>
__global__ __launch_bounds__(256, 3) void gemm_bt_kernel(
    const u16* __restrict__ A, const u16* __restrict__ Bt,
    const float* __restrict__ bias, void* __restrict__ Cv,
    int M, int N, int K, int qcols, float qscale,
    int vcol0 = 0, u16* __restrict__ VT = nullptr)
{
    constexpr int MR = BM / 32;
    __shared__ __attribute__((aligned(16))) u16 As[BM][64];
    __shared__ __attribute__((aligned(16))) u16 Bs[128][64];
    const int tid = threadIdx.x;
    const int lane = tid & 63, wid = tid >> 6;
    const int wr = wid >> 1, wc = wid & 1;
    const int m0 = blockIdx.x * BM, n0 = blockIdx.y * 128;
    const int kz = (KSPLIT > 1) ? blockIdx.z : 0;
    const int Kc = K / KSPLIT;
    const int k0 = kz * Kc;
    const int arow = lane & 15;
    const int kseg = (lane >> 4) * 8;
    const int srow = lane >> 3;
    const int scol = ((lane & 7) ^ srow) * 8;
    const int rswz = (arow & 7) << 3;
    const f32x4 z4 = {0.f, 0.f, 0.f, 0.f};

    f32x4 acc[MR][4];
#pragma unroll
    for (int i = 0; i < MR; ++i)
#pragma unroll
        for (int j = 0; j < 4; ++j) acc[i][j] = z4;

    for (int kt = k0; kt < k0 + Kc; kt += 64) {
        __syncthreads();
#pragma unroll
        for (int i = 0; i < MR; ++i) {
            int ch = wid + i * 4;
            async16(&A[(size_t)(m0 + ch * 8 + srow) * K + kt + scol], &As[ch * 8][0]);
        }
#pragma unroll
        for (int i = 0; i < 4; ++i) {
            int ch = wid + i * 4;
            async16(&Bt[(size_t)(n0 + ch * 8 + srow) * K + kt + scol], &Bs[ch * 8][0]);
        }
        __syncthreads();
#pragma unroll
        for (int ks = 0; ks < 2; ++ks) {
            const int cswz = (ks * 32 + kseg) ^ rswz;
            bf16x8 af[MR], bfr[4];
#pragma unroll
            for (int mi = 0; mi < MR; ++mi)
                af[mi] = *reinterpret_cast<const bf16x8*>(&As[wr * (BM / 2) + mi * 16 + arow][cswz]);
#pragma unroll
            for (int ni = 0; ni < 4; ++ni)
                bfr[ni] = *reinterpret_cast<const bf16x8*>(&Bs[wc * 64 + ni * 16 + arow][cswz]);
#pragma unroll
            for (int mi = 0; mi < MR; ++mi)
#pragma unroll
                for (int ni = 0; ni < 4; ++ni)
                    acc[mi][ni] = __builtin_amdgcn_mfma_f32_16x16x32_bf16(af[mi], bfr[ni], acc[mi][ni], 0, 0, 0);
        }
    }
    const int rrow = (lane >> 4) * 4;
#pragma unroll
    for (int mi = 0; mi < MR; ++mi)
#pragma unroll
        for (int ni = 0; ni < 4; ++ni) {
            int col = n0 + wc * 64 + ni * 16 + arow;
            float bv = (kz == 0) ? bias[col] : 0.f;
            float sc = (col < qcols) ? qscale : 1.f;
            float vv[4];
#pragma unroll
            for (int r = 0; r < 4; ++r) {
                float v = (acc[mi][ni][r] + bv) * sc;
                if (RELU) v = fmaxf(v, 0.f);
                vv[r] = v;
            }
            int row0 = m0 + wr * (BM / 2) + mi * 16 + rrow;
            if (VOUT && col >= vcol0) {
                int hh = (col - vcol0) >> 6, dd = (col - vcol0) & 63;
                int bb = row0 >> 10, s0 = row0 & 1023;
                ushort4 hv = {f2b(vv[0]), f2b(vv[1]), f2b(vv[2]), f2b(vv[3])};
                *reinterpret_cast<ushort4*>(&VT[((size_t)(bb * 16 + hh) * 64 + dd) * 1024 + s0]) = hv;
            } else {
#pragma unroll
                for (int r = 0; r < 4; ++r) {
                    size_t idx = (size_t)kz * M * N + (size_t)(row0 + r) * N + col;
                    if (OUT_BF16) ((u16*)Cv)[idx] = f2b(vv[r]);
                    else          ((float*)Cv)[idx] = vv[r];
                }
            }
        }
}

// ---------------- 256 x (NFRAG*64) tile 8-wave deep-pipelined GEMM ----------------
template<int NFRAG, bool OUT_BF16, bool RELU, int KSPLIT = 1, bool VOUT = false>
__global__ __launch_bounds__(512, 2) void gemm256_kernel(
    const u16* __restrict__ A, const u16* __restrict__ Bt,
    const float* __restrict__ bias, void* __restrict__ Cv,
    int M, int N, int K, int qcols, float qscale,
    int vcol0 = 0, u16* __restrict__ VT = nullptr)
{
    constexpr int BN = NFRAG * 64;
    __shared__ __attribute__((aligned(16))) u16 As[2][256][64];
    __shared__ __attribute__((aligned(16))) u16 Bs[2][BN][64];
    const int tid = threadIdx.x, lane = tid & 63, wid = tid >> 6;
    const int wr = wid >> 2, wc = wid & 3;
    const int gx = gridDim.x, nwg = gridDim.x * gridDim.y;
    int bid = blockIdx.y * gx + blockIdx.x;
    int swz = (bid & 7) * (nwg >> 3) + (bid >> 3);
    const int m0 = (swz % gx) * 256, n0 = (swz / gx) * BN;
    const int kz = (KSPLIT > 1) ? blockIdx.z : 0;
    const int Kc = K / KSPLIT, k0 = kz * Kc, NT = Kc >> 6;
    const int a = lane & 15, g = lane >> 4;
    const int srow = lane >> 3;
    const int scol = ((lane & 7) ^ srow) * 8;
    const int rswz = (a & 7) << 3;
    const f32x4 z4 = {0.f, 0.f, 0.f, 0.f};

    f32x4 acc[8][NFRAG];
#pragma unroll
    for (int i = 0; i < 8; ++i)
#pragma unroll
        for (int j = 0; j < NFRAG; ++j) acc[i][j] = z4;

    auto stageA = [&](int t, int h) {
        int kt = k0 + t * 64;
#pragma unroll
        for (int i = 0; i < 2; ++i) {
            int row = h * 128 + (wid * 2 + i) * 8;
            async16(&A[(size_t)(m0 + row + srow) * K + kt + scol], &As[t & 1][row][0]);
        }
    };
    auto stageBs = [&](int t, int s) {
        int kt = k0 + t * 64;
        int row = s * 64 + wid * 8;
        async16(&Bt[(size_t)(n0 + row + srow) * K + kt + scol], &Bs[t & 1][row][0]);
    };
    auto stageBall = [&](int t) {
#pragma unroll
        for (int s = 0; s < NFRAG; ++s) stageBs(t, s);
    };

    stageA(0, 0); stageA(0, 1); stageBall(0);
    stageA(1, 0); stageA(1, 1); stageBall(1);
    if (NFRAG == 4) asm volatile("s_waitcnt vmcnt(8)" ::: "memory");
    else            asm volatile("s_waitcnt vmcnt(7)" ::: "memory");
    __builtin_amdgcn_s_barrier();
    asm volatile("" ::: "memory");

    for (int t = 0; t < NT; ++t) {
        const int b = t & 1;
        bf16x8 bf[NFRAG][2];
#pragma unroll
        for (int p = 0; p < 4; ++p) {
            bf16x8 af[2][2];
#pragma unroll
            for (int m2 = 0; m2 < 2; ++m2)
#pragma unroll
                for (int ks = 0; ks < 2; ++ks)
                    af[m2][ks] = *reinterpret_cast<const bf16x8*>(
                        &As[b][wr * 128 + (p * 2 + m2) * 16 + a][(ks * 32 + g * 8) ^ rswz]);
            if (p == 0) {
#pragma unroll
                for (int ni = 0; ni < NFRAG; ++ni)
#pragma unroll
                    for (int ks = 0; ks < 2; ++ks)
                        bf[ni][ks] = *reinterpret_cast<const bf16x8*>(
                            &Bs[b][wc * (NFRAG * 16) + ni * 16 + a][(ks * 32 + g * 8) ^ rswz]);
            }
            if (p == 0 && t >= 1 && t + 1 < NT) stageA(t + 1, 0);
            if (p == 1 && t >= 1 && t + 1 < NT) stageA(t + 1, 1);
            if (p == 2 && t + 2 < NT) {
                stageBs(t + 2, 0);
                if (NFRAG >= 2) stageBs(t + 2, 1);
            }
            if (p == 3 && t + 2 < NT) {
#pragma unroll
                for (int s = 2; s < NFRAG; ++s) stageBs(t + 2, s);
            }
            asm volatile("" ::: "memory");
            __builtin_amdgcn_s_barrier();
            asm volatile("" ::: "memory");
            __builtin_amdgcn_s_setprio(1);
#pragma unroll
            for (int ks = 0; ks < 2; ++ks)
#pragma unroll
                for (int m2 = 0; m2 < 2; ++m2)
#pragma unroll
                    for (int ni = 0; ni < NFRAG; ++ni)
                        acc[p * 2 + m2][ni] = __builtin_amdgcn_mfma_f32_16x16x32_bf16(
                            af[m2][ks], bf[ni][ks], acc[p * 2 + m2][ni], 0, 0, 0);
            __builtin_amdgcn_s_setprio(0);
        }
        if (t < NT - 1) {
            if (t < NT - 2) {
                if (NFRAG == 4) asm volatile("s_waitcnt vmcnt(4)" ::: "memory");
                else            asm volatile("s_waitcnt vmcnt(3)" ::: "memory");
            } else {
                asm volatile("s_waitcnt vmcnt(0)" ::: "memory");
            }
            __builtin_amdgcn_s_barrier();
            asm volatile("" ::: "memory");
        }
    }

    const int rrow = g * 4;
#pragma unroll
    for (int mi = 0; mi < 8; ++mi)
#pragma unroll
        for (int ni = 0; ni < NFRAG; ++ni) {
            int col = n0 + wc * (NFRAG * 16) + ni * 16 + a;
            float bv = (kz == 0) ? bias[col] : 0.f;
            float sc = (col < qcols) ? qscale : 1.f;
            float vv[4];
#pragma unroll
            for (int r = 0; r < 4; ++r) {
                float v = (acc[mi][ni][r] + bv) * sc;
                if (RELU) v = fmaxf(v, 0.f);
                vv[r] = v;
            }
            int row0 = m0 + wr * 128 + mi * 16 + rrow;
            if (VOUT && col >= vcol0) {
                int hh = (col - vcol0) >> 6, dd = (col - vcol0) & 63;
                int bb = row0 >> 10, s0 = row0 & 1023;
                ushort4 hv = {f2b(vv[0]), f2b(vv[1]), f2b(vv[2]), f2b(vv[3])};
                *reinterpret_cast<ushort4*>(&VT[((size_t)(bb * 16 + hh) * 64 + dd) * 1024 + s0]) = hv;
            } else {
#pragma unroll
                for (int r = 0; r < 4; ++r) {
                    size_t idx = (size_t)kz * M * N + (size_t)(row0 + r) * N + col;
                    if (OUT_BF16) ((u16*)Cv)[idx] = f2b(vv[r]);
                    else          ((float*)Cv)[idx] = vv[r];
                }
            }
        }
}

// ---------------- flash attention ----------------
__global__ __launch_bounds__(512, 4) void flash_attn_kernel(
    const u16* __restrict__ Q, int ldq, const u16* __restrict__ Kp, int ldk,
    const u16* __restrict__ VT, u16* __restrict__ O,
    const int* __restrict__ vlens, int causal)
{
    __shared__ __attribute__((aligned(16))) u16 Ks[128][64];
    __shared__ __attribute__((aligned(16))) u16 Vs[64][128];
    __shared__ __attribute__((aligned(16))) u16 Ps[128][64];
    const int tid = threadIdx.x, lane = tid & 63, wid = tid >> 6;
    const int bh = blockIdx.x;
    int qb = blockIdx.y;
    if (causal) qb = (bh & 1) ? (7 - qb) : qb;
    const int b = bh >> 4, h = bh & 15;
    const int q0 = qb * 128;
    const int a = lane & 15;
    const int g = lane >> 4;
    const int kseg = g * 8;
    const int srow = lane >> 3;
    const int scol = ((lane & 7) ^ srow) * 8;
    const int vrow = lane >> 4;
    const int rswz = (a & 7) << 3;
    const int vswz = a << 3;
    const f32x4 z4 = {0.f, 0.f, 0.f, 0.f};

    bf16x8 qf[2];
#pragma unroll
    for (int ks = 0; ks < 2; ++ks)
        qf[ks] = *reinterpret_cast<const bf16x8*>(
            &Q[(size_t)(b * SS + q0 + wid * 16 + a) * ldq + h * DHH + ks * 32 + kseg]);

    float m_run = -3e38f, l_run = 0.f;
    f32x4 o[4];
#pragma unroll
    for (int nd = 0; nd < 4; ++nd) o[nd] = z4;

    int vl = causal ? SS : vlens[b];
    int ntiles = causal ? (qb + 1) : ((vl + 127) >> 7);

    for (int kt = 0; kt < ntiles; ++kt) {
        const int kv0 = kt * 128;
        __syncthreads();
#pragma unroll
        for (int i = 0; i < 2; ++i) {
            int ch = wid + i * 8;
            async16(&Kp[(size_t)(b * SS + kv0 + ch * 8 + srow) * ldk + h * DHH + scol], &Ks[ch * 8][0]);
            int cv = wid + i * 8;
            int vs = (cv * 4 + vrow) & 15;
            async16(&VT[(size_t)(bh * DHH + cv * 4 + vrow) * SS + kv0 + ((lane & 15) ^ vs) * 8], &Vs[cv * 4][0]);
        }
        __syncthreads();

        f32x4 st[8];
#pragma unroll
        for (int ni = 0; ni < 8; ++ni) st[ni] = z4;
        __builtin_amdgcn_s_setprio(1);
#pragma unroll
        for (int ks = 0; ks < 2; ++ks) {
            const int cswz = (ks * 32 + kseg) ^ rswz;
            bf16x8 kf[8];
#pragma unroll
            for (int ni = 0; ni < 8; ++ni)
                kf[ni] = *reinterpret_cast<const bf16x8*>(&Ks[ni * 16 + a][cswz]);
#pragma unroll
            for (int ni = 0; ni < 8; ++ni)
                st[ni] = __builtin_amdgcn_mfma_f32_16x16x32_bf16(kf[ni], qf[ks], st[ni], 0, 0, 0);
        }
        __builtin_amdgcn_s_setprio(0);

        bool domask = causal ? (kt == qb) : (kv0 + 128 > vl);
        if (domask) {
            const int qg = q0 + wid * 16 + a;
#pragma unroll
            for (int ni = 0; ni < 8; ++ni)
#pragma unroll
                for (int r = 0; r < 4; ++r) {
                    int cg = kv0 + ni * 16 + 4 * g + r;
                    bool keep = causal ? (cg <= qg) : (cg < vl);
                    if (!keep) st[ni][r] = NEGV;
                }
        }

        float tm = -3e38f;
#pragma unroll
        for (int ni = 0; ni < 8; ++ni)
#pragma unroll
            for (int r = 0; r < 4; ++r) tm = fmaxf(tm, st[ni][r]);
        tm = fmaxf(tm, __shfl_xor(tm, 16));
        tm = fmaxf(tm, __shfl_xor(tm, 32));
        bool need = __any(tm > m_run + 11.0f);
        float corr = 1.f;
        if (need) {
            float nm = fmaxf(m_run, tm);
            corr = exp2_raw(m_run - nm);
            m_run = nm;
        }
        float rs = 0.f;
#pragma unroll
        for (int ni = 0; ni < 8; ++ni)
#pragma unroll
            for (int r = 0; r < 4; ++r) {
                float p = exp2_raw(st[ni][r] - m_run);
                st[ni][r] = p;
                rs += p;
            }
        rs += __shfl_xor(rs, 16);
        rs += __shfl_xor(rs, 32);
        l_run = l_run * corr + rs;

        if (need) {
#pragma unroll
            for (int r = 0; r < 4; ++r) {
                float cr = __shfl(corr, (lane & 48) + 4 * g + r);
#pragma unroll
                for (int nd = 0; nd < 4; ++nd) o[nd][r] *= cr;
            }
        }

#pragma unroll
        for (int hh = 0; hh < 2; ++hh) {
#pragma unroll
            for (int ni4 = 0; ni4 < 4; ++ni4) {
                int ni = hh * 4 + ni4;
                uint2 pw;
                pw.x = (uint32_t)f2b(st[ni][0]) | ((uint32_t)f2b(st[ni][1]) << 16);
                pw.y = (uint32_t)f2b(st[ni][2]) | ((uint32_t)f2b(st[ni][3]) << 16);
                int prow = wid * 16 + a;
                int pcol = (ni4 * 16 + 4 * g) ^ rswz;
                *reinterpret_cast<uint2*>(&Ps[prow][pcol]) = pw;
            }
            __builtin_amdgcn_s_setprio(1);
#pragma unroll
            for (int kk = 0; kk < 2; ++kk) {
                const int kf_ = hh * 2 + kk;
                const int pswz = (kk * 32 + kseg) ^ rswz;
                const int cvswz = (kf_ * 32 + kseg) ^ vswz;
                bf16x8 pa, vb[4];
                pa = *reinterpret_cast<const bf16x8*>(&Ps[wid * 16 + a][pswz]);
#pragma unroll
                for (int nd = 0; nd < 4; ++nd)
                    vb[nd] = *reinterpret_cast<const bf16x8*>(&Vs[nd * 16 + a][cvswz]);
#pragma unroll
                for (int nd = 0; nd < 4; ++nd)
                    o[nd] = __builtin_amdgcn_mfma_f32_16x16x32_bf16(pa, vb[nd], o[nd], 0, 0, 0);
            }
            __builtin_amdgcn_s_setprio(0);
        }
    }

    float il = 1.f / l_run;
#pragma unroll
    for (int r = 0; r < 4; ++r) {
        float ilr = __shfl(il, (lane & 48) + 4 * g + r);
        int row = q0 + wid * 16 + 4 * g + r;
#pragma unroll
        for (int nd = 0; nd < 4; ++nd)
            O[(size_t)(b * SS + row) * DD + h * DHH + nd * 16 + a] = f2b(o[nd][r] * ilr);
    }
}

// ---------------- fused (sum of NP bf16 partials) + residual + LayerNorm ----------------
template<int NP, bool RBF16, bool OUT32>
__global__ void add_ln_kernel(const u16* __restrict__ P, size_t pstride,
                              const void* __restrict__ Rv,
                              const float* __restrict__ g, const float* __restrict__ be,
                              float* __restrict__ out32, u16* __restrict__ out16)
{
    __shared__ float red[4][2];
    const int row = blockIdx.x, tid = threadIdx.x;
    const size_t base = (size_t)row * DD;
    float x0, x1, x2, x3;
    if (RBF16) {
        ushort4 u = *reinterpret_cast<const ushort4*>((const u16*)Rv + base + tid * 4);
        x0 = b2f(u.x); x1 = b2f(u.y); x2 = b2f(u.z); x3 = b2f(u.w);
    } else {
        float4 v = *reinterpret_cast<const float4*>((const float*)Rv + base + tid * 4);
        x0 = v.x; x1 = v.y; x2 = v.z; x3 = v.w;
    }
#pragma unroll
    for (int p = 0; p < NP; ++p) {
        ushort4 u = *reinterpret_cast<const ushort4*>(P + p * pstride + base + tid * 4);
        x0 += b2f(u.x); x1 += b2f(u.y); x2 += b2f(u.z); x3 += b2f(u.w);
    }
    float s = x0 + x1 + x2 + x3;
    float q = x0 * x0 + x1 * x1 + x2 * x2 + x3 * x3;
#pragma unroll
    for (int off = 32; off; off >>= 1) {
        s += __shfl_xor(s, off);
        q += __shfl_xor(q, off);
    }
    if ((tid & 63) == 0) { red[tid >> 6][0] = s; red[tid >> 6][1] = q; }
    __syncthreads();
    s = red[0][0] + red[1][0] + red[2][0] + red[3][0];
    q = red[0][1] + red[1][1] + red[2][1] + red[3][1];
    float mean = s * (1.f / 1024.f);
    float var = q * (1.f / 1024.f) - mean * mean;
    float rstd = rsqrtf(var + 1e-5f);
    int c = tid * 4;
    float o0 = (x0 - mean) * rstd * g[c + 0] + be[c + 0];
    float o1 = (x1 - mean) * rstd * g[c + 1] + be[c + 1];
    float o2 = (x2 - mean) * rstd * g[c + 2] + be[c + 2];
    float o3 = (x3 - mean) * rstd * g[c + 3] + be[c + 3];
    if (OUT32) {
        float4 ov = {o0, o1, o2, o3};
        *reinterpret_cast<float4*>(out32 + base + c) = ov;
    } else {
        ushort4 hv;
        hv.x = f2b(o0); hv.y = f2b(o1); hv.z = f2b(o2); hv.w = f2b(o3);
        *reinterpret_cast<ushort4*>(out16 + base + c) = hv;
    }
}

extern "C" void kernel_launch(void* const* d_in, const int* in_sizes, int n_in,
                              void* d_out, int out_size, void* d_ws, size_t ws_size,
                              hipStream_t stream)
{
    const float* X   = (const float*)d_in[0];
    const float* ENC = (const float*)d_in[1];
    const int*   VL  = (const int*)d_in[2];
    const float* Wq1 = (const float*)d_in[3];  const float* bq1 = (const float*)d_in[4];
    const float* Wk1 = (const float*)d_in[5];  const float* bk1 = (const float*)d_in[6];
    const float* Wv1 = (const float*)d_in[7];  const float* bv1 = (const float*)d_in[8];
    const float* Wo1 = (const float*)d_in[9];  const float* bo1 = (const float*)d_in[10];
    const float* g1  = (const float*)d_in[11]; const float* be1 = (const float*)d_in[12];
    const float* Wq2 = (const float*)d_in[13]; const float* bq2 = (const float*)d_in[14];
    const float* Wk2 = (const float*)d_in[15]; const float* bk2 = (const float*)d_in[16];
    const float* Wv2 = (const float*)d_in[17]; const float* bv2 = (const float*)d_in[18];
    const float* Wo2 = (const float*)d_in[19]; const float* bo2 = (const float*)d_in[20];
    const float* g2  = (const float*)d_in[21]; const float* be2 = (const float*)d_in[22];
    const float* Wf1 = (const float*)d_in[23]; const float* bf1 = (const float*)d_in[24];
    const float* Wf2 = (const float*)d_in[25]; const float* bf2 = (const float*)d_in[26];
    const float* g3  = (const float*)d_in[27]; const float* be3 = (const float*)d_in[28];

    char* ws = (char*)d_ws;
    const size_t MB = 1024 * 1024;
    u16*   XBF  = (u16*)(ws + 0 * MB);
    u16*   ENCB = (u16*)(ws + 8 * MB);
    u16*   WTsq = (u16*)(ws + 16 * MB);
    u16*   WTf1 = (u16*)(ws + 32 * MB);
    u16*   WTf2 = (u16*)(ws + 40 * MB);
    u16*   QKV  = (u16*)(ws + 48 * MB);
    u16*   HF   = (u16*)(ws + 48 * MB);
    u16*   VTb  = (u16*)(ws + 80 * MB);
    u16*   AO   = (u16*)(ws + 88 * MB);
    u16*   P4   = (u16*)(ws + 80 * MB);
    u16*   P16  = (u16*)(ws + 96 * MB);
    u16*   YBF  = (u16*)(ws + 128 * MB);
    u16*   ZBF  = (u16*)(ws + 152 * MB);
    float* B1 = (float*)d_out;
    float* B2 = (float*)d_out + 4096;
    (void)ws_size; (void)in_sizes; (void)n_in; (void)out_size;

    const int M = BB * SS;
    const size_t MN = (size_t)M * DD;
    const float QS = 0.125f * LOG2E;

    W8 w8 = {{Wq1, Wk1, Wv1, Wo1, Wq2, Wk2, Wv2, Wo2}};
    prep_kernel<<<10260, 256, 0, stream>>>(X, ENC, XBF, ENCB, w8, WTsq,
                                           Wf1, WTf1, Wf2, WTf2,
                                           bq1, bk1, bv1, B1, bk2, bv2, B2);

    // ---------- self attention ----------
    gemm256_kernel<3, true, false, 1, true><<<dim3(16, 16), 512, 0, stream>>>(
        XBF, WTsq, B1, QKV, M, 3072, DD, 1024, QS, 2048, VTb);
    flash_attn_kernel<<<dim3(64, 8), 512, 0, stream>>>(QKV, 3072, QKV + 1024, 3072, VTb, AO, VL, 1);
    gemm_bt_kernel<128, true, false, 2><<<dim3(32, 8, 2), 256, 0, stream>>>(AO, WTsq + 3u * 1024 * 1024, bo1, P16, M, DD, DD, 0, 1.f);
    add_ln_kernel<2, true, false><<<M, 256, 0, stream>>>(P16, MN, XBF, g1, be1, nullptr, YBF);

    // ---------- cross attention (R18 exact config: Q2 on BM=64, 512 blocks) ----------
    gemm_bt_kernel<64, true, false><<<dim3(64, 8), 256, 0, stream>>>(YBF, WTsq + 4u * 1024 * 1024, bq2, XBF, M, DD, DD, 1024, QS);
    gemm_bt_kernel<128, true, false, 1, true><<<dim3(32, 16), 256, 0, stream>>>(
        ENCB, WTsq + 5u * 1024 * 1024, B2, QKV, M, 2048, DD, 0, 1.f, 1024, VTb);
    flash_attn_kernel<<<dim3(64, 8), 512, 0, stream>>>(XBF, 1024, QKV, 2048, VTb, AO, VL, 0);
    gemm_bt_kernel<128, true, false, 2><<<dim3(32, 8, 2), 256, 0, stream>>>(AO, WTsq + 7u * 1024 * 1024, bo2, P16, M, DD, DD, 0, 1.f);
    add_ln_kernel<2, true, false><<<M, 256, 0, stream>>>(P16, MN, YBF, g2, be2, nullptr, ZBF);

    // ---------- FFN ----------
    gemm256_kernel<4, true, true><<<dim3(16, 16), 512, 0, stream>>>(ZBF, WTf1, bf1, HF, M, FF, DD, 0, 1.f);
    gemm256_kernel<4, true, false, 4><<<dim3(16, 4, 4), 512, 0, stream>>>(HF, WTf2, bf2, P4, M, DD, FF, 0, 1.f);
    add_ln_kernel<4, true, true><<<M, 256, 0, stream>>>(P4, MN, ZBF, g3, be3, (float*)d_out, nullptr);
}